// Round 2
// baseline (407.281 us; speedup 1.0000x reference)
//
#include <hip/hip_runtime.h>
#include <stdint.h>
#include <stddef.h>

#define K_DIM 4096
#define N_DIM 4096
#define BM 256
#define BN 256
#define BK 64                     // bytes of K per tile = one 16x16x64 substep
#define NT (K_DIM / BK)           // 64 K-tiles
#define SLOT_A (BM * BK)          // 16 KB
#define SLOT_B (BN * BK)          // 16 KB
#define SLOT (SLOT_A + SLOT_B)    // 32 KB
#define LDS_BYTES (4 * SLOT)      // 128 KB ring-4

typedef int v4i __attribute__((ext_vector_type(4)));
typedef uint32_t v4u __attribute__((ext_vector_type(4)));

__device__ __forceinline__ void load_lds16(const void* gp, void* lp) {
  __builtin_amdgcn_global_load_lds(
      (__attribute__((address_space(1))) void*)(uintptr_t)gp,
      (__attribute__((address_space(3))) void*)(uintptr_t)lp,
      16, 0, 0);
}

__device__ __forceinline__ uint32_t pack4(int a, int b, int c, int d) {
  return (uint32_t)(uint8_t)a | ((uint32_t)(uint8_t)b << 8) |
         ((uint32_t)(uint8_t)c << 16) | ((uint32_t)(uint8_t)d << 24);
}

// ---------------- Kernel 0: pack weight int32 -> int8 ----------------------
__global__ __launch_bounds__(256) void pack_w_kernel(
    const int4* __restrict__ w32, v4u* __restrict__ w8, int n16) {
  int i = blockIdx.x * 256 + threadIdx.x;
  if (i >= n16) return;
  int4 a = w32[i * 4 + 0], b = w32[i * 4 + 1], c = w32[i * 4 + 2], d = w32[i * 4 + 3];
  v4u o;
  o.x = pack4(a.x, a.y, a.z, a.w);
  o.y = pack4(b.x, b.y, b.z, b.w);
  o.z = pack4(c.x, c.y, c.z, c.w);
  o.w = pack4(d.x, d.y, d.z, d.w);
  w8[i] = o;
}

// ---------------- Kernel 1: quantize fp32 -> int8 --------------------------
// Exact fp32 division + RNE to match jnp.round(x / INPUT_SCALE).
__global__ __launch_bounds__(256) void quant_kernel(
    const float4* __restrict__ x, v4u* __restrict__ xq, int n16) {
  int i = blockIdx.x * 256 + threadIdx.x;
  if (i >= n16) return;
  v4u o;
#pragma unroll
  for (int j = 0; j < 4; ++j) {
    float4 v = x[i * 4 + j];
    float r0 = fminf(fmaxf(rintf(v.x / 0.05f), -128.f), 127.f);
    float r1 = fminf(fmaxf(rintf(v.y / 0.05f), -128.f), 127.f);
    float r2 = fminf(fmaxf(rintf(v.z / 0.05f), -128.f), 127.f);
    float r3 = fminf(fmaxf(rintf(v.w / 0.05f), -128.f), 127.f);
    o[j] = pack4((int)r0, (int)r1, (int)r2, (int)r3);
  }
  xq[i] = o;
}

// ---------------- Kernel 2: int8 GEMM, 256x256 tile, ring-4 pipeline -------
// Geometry (m201-style, adapted to i8): 256x256 block, 8 waves (2M x 4N),
// wave tile 128x64. BK=64 B -> one 16x16x64 substep per K-tile, 32 MFMA per
// wave per tile in 2 phases of 16 (split on M-halves; bf[] regs reused in
// phase 2, so ph1 = 8 ds_read_b128, ph2 = 4).
//
// Why this geometry: rounds 0/1 both measured MfmaUtil 36.5% with identical
// LDS-bytes/op (64x64 wave tiles); LDS port traffic (frag reads 128 KB +
// staging 48 KB per 128B-K-tile) exceeded MFMA cycles by 1.6x -> LDS-BW
// bound. 128x64 wave tiles cut frag traffic 1.5x: per BK=64 tile, reads
// 96 KB + staging 32 KB ~ balanced against 1306 MFMA cy/SIMD.
//
// LDS: ring of 4 slots (32 KB). Stage 3 tiles ahead; slot (t+3)%4's previous
// occupant t-1 was fully consumed before tile t began (each wave's lgkm(0)
// precedes its MFMAs which precede t-1's final barrier) -> race-free.
// vmcnt(8) once per tile boundary (t+1 landed; t+2,t+3's 8 loads in flight);
// never 0 until the 2-tile tail.
//
// Swizzle: 4 chunks of 16 B per row; (row, kv) stored at chunk kv ^ (row&3).
// Frag reads then alias at most 2-way per bank (free, m136). Staging applies
// the inverse permutation on the per-lane GLOBAL source address
// (global_load_lds LDS dst is rigid: base + lane*16).
//
// XCD swizzle: 512 blocks = 32 m x 16 n; 2 n-blocks per XCD (2 MB of B
// L2-resident), all XCDs sweep m together so A panels are LLC-shared.
__global__ __launch_bounds__(512, 2) void gemm_i8_kernel(
    const int8_t* __restrict__ A,     // [M, K] quantized activations
    const int8_t* __restrict__ B,     // [N, K] weight (packed int8)
    const float* __restrict__ bias,   // [N]
    float* __restrict__ C,            // [M, N]
    int M) {
  extern __shared__ __align__(16) int8_t lds[];

  const int tid  = threadIdx.x;
  const int lane = tid & 63;
  const int wave = tid >> 6;
  const int wm   = wave >> 2;   // 0..1  (128-row band)
  const int wn   = wave & 3;    // 0..3  (64-col band)
  const int quad = lane >> 4;
  const int lrow = lane & 15;

  const int bid   = blockIdx.x;
  const int xcd   = bid & 7;
  const int slot  = bid >> 3;            // 0..63
  const int n_blk = xcd * 2 + (slot & 1);
  const int m_blk = slot >> 1;           // 0..31
  const int m0 = m_blk * BM;
  const int n0 = n_blk * BN;

  // Fragment read offsets (byte offsets within a slot's A / B region).
  // Frag i reads row wm*128 + i*16 + lrow, logical chunk = quad,
  // physical chunk = quad ^ (row&3) = quad ^ (lrow&3).
  const int swz   = quad ^ (lrow & 3);
  const int a_off = (wm * 128 + lrow) * 64 + swz * 16;
  const int b_off = (wn * 64 + lrow) * 64 + swz * 16;

  // Staging: slot region = 256 rows x 4 chunks of 16 B = 1024 chunks; thread
  // covers chunks c = q*512 + tid (q=0,1). LDS dst = region + c*16 (linear,
  // as global_load_lds requires); global src row = c>>2, logical chunk =
  // (c&3) ^ (row&3)  [inverse swizzle].
  const int8_t* ag[2];
  const int8_t* bg[2];
  int st_lds[2];
#pragma unroll
  for (int q = 0; q < 2; ++q) {
    int c = q * 512 + tid;
    int row = c >> 2;
    int lc = (c & 3) ^ (row & 3);
    ag[q] = A + (size_t)(m0 + row) * K_DIM + lc * 16;
    bg[q] = B + (size_t)(n0 + row) * K_DIM + lc * 16;
    st_lds[q] = c * 16;
  }

  // Prologue: stage tiles 0,1,2 into slots 0,1,2 (12 loads / thread).
#pragma unroll
  for (int kt = 0; kt < 3; ++kt) {
    int8_t* sb = lds + kt * SLOT;
#pragma unroll
    for (int q = 0; q < 2; ++q) load_lds16(ag[q] + kt * BK, sb + st_lds[q]);
#pragma unroll
    for (int q = 0; q < 2; ++q) load_lds16(bg[q] + kt * BK, sb + SLOT_A + st_lds[q]);
  }
#pragma unroll
  for (int q = 0; q < 2; ++q) { ag[q] += 3 * BK; bg[q] += 3 * BK; }

  asm volatile("s_waitcnt vmcnt(8)" ::: "memory");  // tile 0 landed
  __builtin_amdgcn_s_barrier();
  __builtin_amdgcn_sched_barrier(0);

  v4i acc[8][4] = {};

#pragma unroll 1
  for (int t = 0; t < NT; ++t) {
    const int rb = (t & 3) * SLOT;        // read slot
    const int wb = ((t + 3) & 3) * SLOT;  // stage target (tile t+3)
    const bool pf = (t < NT - 3);

    // ---- phase 1: M-half 0 (A-frags 0..3) x all B-frags ----
    v4i af[4], bf[4];
#pragma unroll
    for (int i = 0; i < 4; ++i)
      af[i] = *(const v4i*)(lds + rb + a_off + i * 1024);
#pragma unroll
    for (int j = 0; j < 4; ++j)
      bf[j] = *(const v4i*)(lds + rb + SLOT_A + b_off + j * 1024);
    if (pf) {
      load_lds16(ag[0], lds + wb + st_lds[0]);
      load_lds16(ag[1], lds + wb + st_lds[1]);
    }
    __builtin_amdgcn_s_barrier();
    __builtin_amdgcn_sched_barrier(0);
    asm volatile("s_waitcnt lgkmcnt(0)" ::: "memory");
    __builtin_amdgcn_sched_barrier(0);
    __builtin_amdgcn_s_setprio(1);
#pragma unroll
    for (int i = 0; i < 4; ++i)
#pragma unroll
      for (int j = 0; j < 4; ++j)
        acc[i][j] = __builtin_amdgcn_mfma_i32_16x16x64_i8(af[i], bf[j],
                                                          acc[i][j], 0, 0, 0);
    __builtin_amdgcn_s_setprio(0);
    __builtin_amdgcn_sched_barrier(0);
    __builtin_amdgcn_s_barrier();

    // ---- phase 2: M-half 1 (A-frags 4..7), bf[] reused from registers ----
#pragma unroll
    for (int i = 0; i < 4; ++i)
      af[i] = *(const v4i*)(lds + rb + a_off + (4 + i) * 1024);
    if (pf) {
      load_lds16(bg[0], lds + wb + SLOT_A + st_lds[0]);
      load_lds16(bg[1], lds + wb + SLOT_A + st_lds[1]);
      ag[0] += BK; ag[1] += BK; bg[0] += BK; bg[1] += BK;
    }
    __builtin_amdgcn_s_barrier();
    __builtin_amdgcn_sched_barrier(0);
    asm volatile("s_waitcnt lgkmcnt(0)" ::: "memory");
    __builtin_amdgcn_sched_barrier(0);
    __builtin_amdgcn_s_setprio(1);
#pragma unroll
    for (int i = 0; i < 4; ++i)
#pragma unroll
      for (int j = 0; j < 4; ++j)
        acc[4 + i][j] = __builtin_amdgcn_mfma_i32_16x16x64_i8(af[i], bf[j],
                                                              acc[4 + i][j], 0, 0, 0);
    __builtin_amdgcn_s_setprio(0);
    __builtin_amdgcn_sched_barrier(0);
    // Tile boundary: tile t+1 must be landed; keep t+2/t+3 loads in flight.
    if (t < NT - 3) {
      asm volatile("s_waitcnt vmcnt(8)" ::: "memory");
    } else if (t == NT - 3) {
      asm volatile("s_waitcnt vmcnt(4)" ::: "memory");
    } else if (t == NT - 2) {
      asm volatile("s_waitcnt vmcnt(0)" ::: "memory");
    }
    __builtin_amdgcn_s_barrier();
    __builtin_amdgcn_sched_barrier(0);
  }

  // Epilogue: y = 0.01 * acc + bias[n]
#pragma unroll
  for (int j = 0; j < 4; ++j) {
    const int n = n0 + wn * 64 + j * 16 + lrow;
    const float bn = bias[n];
#pragma unroll
    for (int i = 0; i < 8; ++i) {
      const int mb = m0 + wm * 128 + i * 16 + quad * 4;
#pragma unroll
      for (int r = 0; r < 4; ++r)
        C[(size_t)(mb + r) * N_DIM + n] = 0.01f * (float)acc[i][j][r] + bn;
    }
  }
}

extern "C" void kernel_launch(void* const* d_in, const int* in_sizes, int n_in,
                              void* d_out, int out_size, void* d_ws, size_t ws_size,
                              hipStream_t stream) {
  static bool inited = false;
  if (!inited) {
    (void)hipFuncSetAttribute(reinterpret_cast<const void*>(gemm_i8_kernel),
                              hipFuncAttributeMaxDynamicSharedMemorySize,
                              LDS_BYTES);
    inited = true;
  }

  const float* x    = (const float*)d_in[0];
  const int*   w32  = (const int*)d_in[1];   // harness stores int8 input as int32
  const float* bias = (const float*)d_in[2];
  float* out = (float*)d_out;
  const int M = in_sizes[0] / K_DIM;  // 8192

  int8_t* xq = (int8_t*)d_ws;                              // M*K
  int8_t* wq = (int8_t*)d_ws + (size_t)M * K_DIM;          // N*K

  const int nw16 = (N_DIM * K_DIM) / 16;
  pack_w_kernel<<<(nw16 + 255) / 256, 256, 0, stream>>>(
      (const int4*)w32, (v4u*)wq, nw16);

  const int n16 = (M * K_DIM) / 16;
  quant_kernel<<<(n16 + 255) / 256, 256, 0, stream>>>(
      (const float4*)x, (v4u*)xq, n16);

  const int nblocks = (M / BM) * (N_DIM / BN);  // 512
  gemm_i8_kernel<<<nblocks, 512, LDS_BYTES, stream>>>(xq, wq, bias, out, M);
}

// Round 4
// 390.284 us; speedup vs baseline: 1.0436x; 1.0436x over previous
//
#include <hip/hip_runtime.h>
#include <stdint.h>
#include <stddef.h>

#define K_DIM 4096
#define N_DIM 4096
#define BM 256
#define BN 256
#define BK 128                    // bytes of K per tile; 2 k-slices of 64
#define NT (K_DIM / BK)           // 32 K-tiles
#define REG_A (BM * BK)           // 32 KB  (A region within a slot)
#define REG_B (BN * BK)           // 32 KB
#define SLOT (REG_A + REG_B)      // 64 KB
#define LDS_BYTES (2 * SLOT)      // 128 KB double buffer
#define HALF 16384                // bytes per staged half (128 rows x 128 B)

typedef int v4i __attribute__((ext_vector_type(4)));
typedef uint32_t v4u __attribute__((ext_vector_type(4)));

__device__ __forceinline__ void load_lds16(const void* gp, void* lp) {
  __builtin_amdgcn_global_load_lds(
      (__attribute__((address_space(1))) void*)(uintptr_t)gp,
      (__attribute__((address_space(3))) void*)(uintptr_t)lp,
      16, 0, 0);
}

__device__ __forceinline__ uint32_t pack4(int a, int b, int c, int d) {
  return (uint32_t)(uint8_t)a | ((uint32_t)(uint8_t)b << 8) |
         ((uint32_t)(uint8_t)c << 16) | ((uint32_t)(uint8_t)d << 24);
}

// ---------------- Kernel 0: pack weight int32 -> int8 ----------------------
__global__ __launch_bounds__(256) void pack_w_kernel(
    const int4* __restrict__ w32, v4u* __restrict__ w8, int n16) {
  int i = blockIdx.x * 256 + threadIdx.x;
  if (i >= n16) return;
  int4 a = w32[i * 4 + 0], b = w32[i * 4 + 1], c = w32[i * 4 + 2], d = w32[i * 4 + 3];
  v4u o;
  o.x = pack4(a.x, a.y, a.z, a.w);
  o.y = pack4(b.x, b.y, b.z, b.w);
  o.z = pack4(c.x, c.y, c.z, c.w);
  o.w = pack4(d.x, d.y, d.z, d.w);
  w8[i] = o;
}

// ---------------- Kernel 1: quantize fp32 -> int8 --------------------------
// Exact fp32 division + RNE to match jnp.round(x / INPUT_SCALE).
__global__ __launch_bounds__(256) void quant_kernel(
    const float4* __restrict__ x, v4u* __restrict__ xq, int n16) {
  int i = blockIdx.x * 256 + threadIdx.x;
  if (i >= n16) return;
  v4u o;
#pragma unroll
  for (int j = 0; j < 4; ++j) {
    float4 v = x[i * 4 + j];
    float r0 = fminf(fmaxf(rintf(v.x / 0.05f), -128.f), 127.f);
    float r1 = fminf(fmaxf(rintf(v.y / 0.05f), -128.f), 127.f);
    float r2 = fminf(fmaxf(rintf(v.z / 0.05f), -128.f), 127.f);
    float r3 = fminf(fmaxf(rintf(v.w / 0.05f), -128.f), 127.f);
    o[j] = pack4((int)r0, (int)r1, (int)r2, (int)r3);
  }
  xq[i] = o;
}

// ---------------- Kernel 2: int8 GEMM, m201-style 4-fine-phase schedule ----
// 256x256 tile, 8 waves (2M x 4N), wave tile 128x64. BK=128 B -> 2 k-slices
// of 64 per MFMA. Per K-tile: 4 phases, each = one C-quadrant of the wave
// tile: {ds_read frags, stage ONE half-tile (2 global_load_lds), barrier,
// lgkm(0), setprio(1), 16 MFMA, setprio(0), counted vmcnt(4), barrier}.
// Zigzag quadrant order (Q00,Q01,Q11,Q10): a-half held 2 phases, both
// b-halves held in regs -> per-phase reads 12/4/8/0 (24 b128/tile minimum).
//
// Staged halves are STRIPE-INTERLEAVED so each wave's phase-p frags live
// entirely in one staged half with >=3-phase lead:
//   A-even = 64-row stripes {0-63,128-191}   (every wave's a-frags 0-3)
//   A-odd  = {64-127,192-255}                (a-frags 4-7)
//   B-even = 32-row stripes {0-31,64-95,...} (every wave's b-frags 0-1)
//   B-odd  = +32                             (b-frags 2-3)
// LDS row r_l in [0,128) of each region half maps to the stripe-interleaved
// global row; ds_read row formulas stay linear in (wm/wn, frag, lrow).
//
// Stage issue order per tile t (for tile t+1): P1->A-even, P2->B-even,
// P3->B-odd, P4->A-odd. vmcnt(4) at ends of P1/P2/P4 keeps 4-8 loads in
// flight, never draining to 0 until the peeled last tile (T4 discipline).
// vmcnt ledger (steady state at tile entry: {BO(t)x2, AO(t)x2} in flight):
// post-P1 vmcnt(4) retires BO(t); post-P2 vmcnt(4) retires AO(t); post-P4
// vmcnt(4) retires AE/BE(t+1). Peeled tail drains 4->2->0.
//
// Swizzle (round-0 verified, 0 conflicts): 16B chunk kv of row r stored at
// phys chunk kv ^ (r&7); staging permutes the per-lane GLOBAL source addr
// (global_load_lds LDS dst is rigid: base + lane*16). All fragment rows
// satisfy idx&7 == lrow&7, so the read-side XOR uses lrow&7.
//
// dbuf-2 x 64 KB slots = 128 KB -> 1 block/CU; launch_bounds(512,1) so the
// register allocator has full headroom (LDS already caps occupancy).
__global__ __launch_bounds__(512, 1) void gemm_i8_kernel(
    const int8_t* __restrict__ A,     // [M, K] quantized activations
    const int8_t* __restrict__ B,     // [N, K] weight (packed int8)
    const float* __restrict__ bias,   // [N]
    float* __restrict__ C,            // [M, N]
    int M) {
  extern __shared__ __align__(16) int8_t lds[];

  const int tid  = threadIdx.x;
  const int lane = tid & 63;
  const int wave = tid >> 6;
  const int wm   = wave >> 2;   // 0..1  (128-row band)
  const int wn   = wave & 3;    // 0..3  (64-col band)
  const int quad = lane >> 4;
  const int lrow = lane & 15;
  const int k7   = lrow & 7;

  const int bid   = blockIdx.x;
  const int xcd   = bid & 7;
  const int slot  = bid >> 3;            // 0..63
  const int n_blk = xcd * 2 + (slot & 1);
  const int m_blk = slot >> 1;           // 0..31
  const int m0 = m_blk * BM;
  const int n0 = n_blk * BN;

  // Fragment read bases (byte offsets; add slot base at use).
  const int cs0  = (quad ^ k7) * 16;        // k-slice 0 chunk (swizzled)
  const int cs1  = ((4 + quad) ^ k7) * 16;  // k-slice 1 chunk
  const int aoff = (wm * 64 + lrow) * 128;          // A region, a-half 0
  const int boff = REG_A + (wn * 32 + lrow) * 128;  // B region, b-half 0

  // Staging source pointers (stripe-interleaved halves, inverse swizzle on
  // the global chunk). Chunk c = q*512 + tid; idx = c>>3 = row-in-half.
  const int8_t *pAe[2], *pAo[2], *pBe[2], *pBo[2];
  int dstc[2];
#pragma unroll
  for (int q = 0; q < 2; ++q) {
    int c   = q * 512 + tid;
    int idx = c >> 3;
    int lc  = (c & 7) ^ (idx & 7);
    int gA  = ((idx & 64) << 1) | (idx & 63);   // A-even stripe row
    int gB  = ((idx & 96) << 1) | (idx & 31);   // B-even stripe row
    pAe[q] = A + (size_t)(m0 + gA) * K_DIM + lc * 16;
    pAo[q] = A + (size_t)(m0 + gA + 64) * K_DIM + lc * 16;
    pBe[q] = B + (size_t)(n0 + gB) * K_DIM + lc * 16;
    pBo[q] = B + (size_t)(n0 + gB + 32) * K_DIM + lc * 16;
    dstc[q] = c * 16;
  }

#define ST_AE(ws) { load_lds16(pAe[0], lds + (ws) + dstc[0]); \
                    load_lds16(pAe[1], lds + (ws) + dstc[1]); }
#define ST_AO(ws) { load_lds16(pAo[0], lds + (ws) + HALF + dstc[0]); \
                    load_lds16(pAo[1], lds + (ws) + HALF + dstc[1]); }
#define ST_BE(ws) { load_lds16(pBe[0], lds + (ws) + REG_A + dstc[0]); \
                    load_lds16(pBe[1], lds + (ws) + REG_A + dstc[1]); }
#define ST_BO(ws) { load_lds16(pBo[0], lds + (ws) + REG_A + HALF + dstc[0]); \
                    load_lds16(pBo[1], lds + (ws) + REG_A + HALF + dstc[1]); }
#define ADV() { pAe[0] += BK; pAe[1] += BK; pAo[0] += BK; pAo[1] += BK; \
                pBe[0] += BK; pBe[1] += BK; pBo[0] += BK; pBo[1] += BK; }
#define MFMA(d, x, y) d = __builtin_amdgcn_mfma_i32_16x16x64_i8(x, y, d, 0, 0, 0)

  // Prologue: stage tile 0 (order Ae,Be,Bo,Ao = in-loop FIFO order).
  ST_AE(0); ST_BE(0); ST_BO(0); ST_AO(0);
  ADV();
  asm volatile("s_waitcnt vmcnt(4)" ::: "memory");  // Ae,Be landed
  __builtin_amdgcn_s_barrier();
  __builtin_amdgcn_sched_barrier(0);

  v4i acc[8][4] = {};
  int rs = 0;

#pragma unroll 1
  for (int t = 0; t < NT - 1; ++t) {
    const int ws = rs ^ SLOT;
    v4i a0[4][2], a1[4][2], b0[2][2], b1[2][2];

    // ---- P1: Q00 (a-half0 x b-half0) -- 12 reads, stage A-even ----
#pragma unroll
    for (int i = 0; i < 4; ++i) {
      a0[i][0] = *(const v4i*)(lds + rs + aoff + i * 2048 + cs0);
      a0[i][1] = *(const v4i*)(lds + rs + aoff + i * 2048 + cs1);
    }
#pragma unroll
    for (int j = 0; j < 2; ++j) {
      b0[j][0] = *(const v4i*)(lds + rs + boff + j * 2048 + cs0);
      b0[j][1] = *(const v4i*)(lds + rs + boff + j * 2048 + cs1);
    }
    ST_AE(ws);
    __builtin_amdgcn_s_barrier();
    __builtin_amdgcn_sched_barrier(0);
    asm volatile("s_waitcnt lgkmcnt(0)" ::: "memory");
    __builtin_amdgcn_sched_barrier(0);
    __builtin_amdgcn_s_setprio(1);
#pragma unroll
    for (int i = 0; i < 4; ++i)
#pragma unroll
      for (int j = 0; j < 2; ++j) {
        MFMA(acc[i][j], a0[i][0], b0[j][0]);
        MFMA(acc[i][j], a0[i][1], b0[j][1]);
      }
    __builtin_amdgcn_s_setprio(0);
    __builtin_amdgcn_sched_barrier(0);
    asm volatile("s_waitcnt vmcnt(4)" ::: "memory");  // B-odd(t) landed
    __builtin_amdgcn_s_barrier();
    __builtin_amdgcn_sched_barrier(0);

    // ---- P2: Q01 (a-half0 x b-half1) -- 4 reads, stage B-even ----
#pragma unroll
    for (int j = 0; j < 2; ++j) {
      b1[j][0] = *(const v4i*)(lds + rs + boff + HALF + j * 2048 + cs0);
      b1[j][1] = *(const v4i*)(lds + rs + boff + HALF + j * 2048 + cs1);
    }
    ST_BE(ws);
    __builtin_amdgcn_s_barrier();
    __builtin_amdgcn_sched_barrier(0);
    asm volatile("s_waitcnt lgkmcnt(0)" ::: "memory");
    __builtin_amdgcn_sched_barrier(0);
    __builtin_amdgcn_s_setprio(1);
#pragma unroll
    for (int i = 0; i < 4; ++i)
#pragma unroll
      for (int j = 0; j < 2; ++j) {
        MFMA(acc[i][2 + j], a0[i][0], b1[j][0]);
        MFMA(acc[i][2 + j], a0[i][1], b1[j][1]);
      }
    __builtin_amdgcn_s_setprio(0);
    __builtin_amdgcn_sched_barrier(0);
    asm volatile("s_waitcnt vmcnt(4)" ::: "memory");  // A-odd(t) landed
    __builtin_amdgcn_s_barrier();
    __builtin_amdgcn_sched_barrier(0);

    // ---- P3: Q11 (a-half1 x b-half1) -- 8 reads, stage B-odd ----
#pragma unroll
    for (int i = 0; i < 4; ++i) {
      a1[i][0] = *(const v4i*)(lds + rs + aoff + HALF + i * 2048 + cs0);
      a1[i][1] = *(const v4i*)(lds + rs + aoff + HALF + i * 2048 + cs1);
    }
    ST_BO(ws);
    __builtin_amdgcn_s_barrier();
    __builtin_amdgcn_sched_barrier(0);
    asm volatile("s_waitcnt lgkmcnt(0)" ::: "memory");
    __builtin_amdgcn_sched_barrier(0);
    __builtin_amdgcn_s_setprio(1);
#pragma unroll
    for (int i = 0; i < 4; ++i)
#pragma unroll
      for (int j = 0; j < 2; ++j) {
        MFMA(acc[4 + i][2 + j], a1[i][0], b1[j][0]);
        MFMA(acc[4 + i][2 + j], a1[i][1], b1[j][1]);
      }
    __builtin_amdgcn_s_setprio(0);
    __builtin_amdgcn_sched_barrier(0);
    __builtin_amdgcn_s_barrier();   // no vmcnt: P4 reads nothing new
    __builtin_amdgcn_sched_barrier(0);

    // ---- P4: Q10 (a-half1 x b-half0, regs) -- 0 reads, stage A-odd ----
    ST_AO(ws);
    __builtin_amdgcn_s_setprio(1);
#pragma unroll
    for (int i = 0; i < 4; ++i)
#pragma unroll
      for (int j = 0; j < 2; ++j) {
        MFMA(acc[4 + i][j], a1[i][0], b0[j][0]);
        MFMA(acc[4 + i][j], a1[i][1], b0[j][1]);
      }
    __builtin_amdgcn_s_setprio(0);
    __builtin_amdgcn_sched_barrier(0);
    ADV();
    asm volatile("s_waitcnt vmcnt(4)" ::: "memory");  // Ae,Be(t+1) landed
    __builtin_amdgcn_s_barrier();
    __builtin_amdgcn_sched_barrier(0);

    rs ^= SLOT;
  }

  // ---- Peeled last tile (no staging; drain counted) ----
  {
    v4i a0[4][2], a1[4][2], b0[2][2], b1[2][2];
#pragma unroll
    for (int i = 0; i < 4; ++i) {
      a0[i][0] = *(const v4i*)(lds + rs + aoff + i * 2048 + cs0);
      a0[i][1] = *(const v4i*)(lds + rs + aoff + i * 2048 + cs1);
    }
#pragma unroll
    for (int j = 0; j < 2; ++j) {
      b0[j][0] = *(const v4i*)(lds + rs + boff + j * 2048 + cs0);
      b0[j][1] = *(const v4i*)(lds + rs + boff + j * 2048 + cs1);
    }
    asm volatile("s_waitcnt lgkmcnt(0)" ::: "memory");
    __builtin_amdgcn_sched_barrier(0);
#pragma unroll
    for (int i = 0; i < 4; ++i)
#pragma unroll
      for (int j = 0; j < 2; ++j) {
        MFMA(acc[i][j], a0[i][0], b0[j][0]);
        MFMA(acc[i][j], a0[i][1], b0[j][1]);
      }
    asm volatile("s_waitcnt vmcnt(2)" ::: "memory");  // B-odd landed
    __builtin_amdgcn_s_barrier();
    __builtin_amdgcn_sched_barrier(0);
#pragma unroll
    for (int j = 0; j < 2; ++j) {
      b1[j][0] = *(const v4i*)(lds + rs + boff + HALF + j * 2048 + cs0);
      b1[j][1] = *(const v4i*)(lds + rs + boff + HALF + j * 2048 + cs1);
    }
    asm volatile("s_waitcnt lgkmcnt(0)" ::: "memory");
    __builtin_amdgcn_sched_barrier(0);
#pragma unroll
    for (int i = 0; i < 4; ++i)
#pragma unroll
      for (int j = 0; j < 2; ++j) {
        MFMA(acc[i][2 + j], a0[i][0], b1[j][0]);
        MFMA(acc[i][2 + j], a0[i][1], b1[j][1]);
      }
    asm volatile("s_waitcnt vmcnt(0)" ::: "memory");  // A-odd landed
    __builtin_amdgcn_s_barrier();
    __builtin_amdgcn_sched_barrier(0);
#pragma unroll
    for (int i = 0; i < 4; ++i) {
      a1[i][0] = *(const v4i*)(lds + rs + aoff + HALF + i * 2048 + cs0);
      a1[i][1] = *(const v4i*)(lds + rs + aoff + HALF + i * 2048 + cs1);
    }
    asm volatile("s_waitcnt lgkmcnt(0)" ::: "memory");
    __builtin_amdgcn_sched_barrier(0);
#pragma unroll
    for (int i = 0; i < 4; ++i)
#pragma unroll
      for (int j = 0; j < 2; ++j) {
        MFMA(acc[4 + i][2 + j], a1[i][0], b1[j][0]);
        MFMA(acc[4 + i][2 + j], a1[i][1], b1[j][1]);
        MFMA(acc[4 + i][j],     a1[i][0], b0[j][0]);
        MFMA(acc[4 + i][j],     a1[i][1], b0[j][1]);
      }
  }
#undef ST_AE
#undef ST_AO
#undef ST_BE
#undef ST_BO
#undef ADV
#undef MFMA

  // Epilogue: y = 0.01 * acc + bias[n]
  // acc[p][jj]: row = wm*128 + (p>>2)*64 + (p&3)*16, col = wn*64 +
  // (jj>>1)*32 + (jj&1)*16. C/D frag: col = lane&15, row = quad*4 + r.
#pragma unroll
  for (int jj = 0; jj < 4; ++jj) {
    const int n = n0 + wn * 64 + (jj >> 1) * 32 + (jj & 1) * 16 + lrow;
    const float bn = bias[n];
#pragma unroll
    for (int p = 0; p < 8; ++p) {
      const int mb = m0 + wm * 128 + (p >> 2) * 64 + (p & 3) * 16 + quad * 4;
#pragma unroll
      for (int r = 0; r < 4; ++r)
        C[(size_t)(mb + r) * N_DIM + n] = 0.01f * (float)acc[p][jj][r] + bn;
    }
  }
}

extern "C" void kernel_launch(void* const* d_in, const int* in_sizes, int n_in,
                              void* d_out, int out_size, void* d_ws, size_t ws_size,
                              hipStream_t stream) {
  static bool inited = false;
  if (!inited) {
    (void)hipFuncSetAttribute(reinterpret_cast<const void*>(gemm_i8_kernel),
                              hipFuncAttributeMaxDynamicSharedMemorySize,
                              LDS_BYTES);
    inited = true;
  }

  const float* x    = (const float*)d_in[0];
  const int*   w32  = (const int*)d_in[1];   // harness stores int8 input as int32
  const float* bias = (const float*)d_in[2];
  float* out = (float*)d_out;
  const int M = in_sizes[0] / K_DIM;  // 8192

  int8_t* xq = (int8_t*)d_ws;                              // M*K
  int8_t* wq = (int8_t*)d_ws + (size_t)M * K_DIM;          // N*K

  const int nw16 = (N_DIM * K_DIM) / 16;
  pack_w_kernel<<<(nw16 + 255) / 256, 256, 0, stream>>>(
      (const int4*)w32, (v4u*)wq, nw16);

  const int n16 = (M * K_DIM) / 16;
  quant_kernel<<<(n16 + 255) / 256, 256, 0, stream>>>(
      (const float4*)x, (v4u*)xq, n16);

  const int nblocks = (M / BM) * (N_DIM / BN);  // 512
  gemm_i8_kernel<<<nblocks, 512, LDS_BYTES, stream>>>(xq, wq, bias, out, M);
}

// Round 5
// 388.376 us; speedup vs baseline: 1.0487x; 1.0049x over previous
//
#include <hip/hip_runtime.h>
#include <stdint.h>
#include <stddef.h>

#define K_DIM 4096
#define N_DIM 4096
#define BM 256
#define BN 256
#define BK 128                    // bytes of K per tile; 2 k-slices of 64
#define NT (K_DIM / BK)           // 32 K-tiles
#define REG_A (BM * BK)           // 32 KB  (A region within a slot)
#define REG_B (BN * BK)           // 32 KB
#define SLOT (REG_A + REG_B)      // 64 KB
#define LDS_BYTES (2 * SLOT)      // 128 KB double buffer
#define HALF 16384                // bytes per staged half (128 rows x 128 B)

typedef int v4i __attribute__((ext_vector_type(4)));
typedef uint32_t v4u __attribute__((ext_vector_type(4)));

__device__ __forceinline__ void load_lds16(const void* gp, void* lp) {
  __builtin_amdgcn_global_load_lds(
      (__attribute__((address_space(1))) void*)(uintptr_t)gp,
      (__attribute__((address_space(3))) void*)(uintptr_t)lp,
      16, 0, 0);
}

__device__ __forceinline__ uint32_t pack4(int a, int b, int c, int d) {
  return (uint32_t)(uint8_t)a | ((uint32_t)(uint8_t)b << 8) |
         ((uint32_t)(uint8_t)c << 16) | ((uint32_t)(uint8_t)d << 24);
}

// ---------------- Kernel 0: pack weight int32 -> int8 ----------------------
__global__ __launch_bounds__(256) void pack_w_kernel(
    const int4* __restrict__ w32, v4u* __restrict__ w8, int n16) {
  int i = blockIdx.x * 256 + threadIdx.x;
  if (i >= n16) return;
  int4 a = w32[i * 4 + 0], b = w32[i * 4 + 1], c = w32[i * 4 + 2], d = w32[i * 4 + 3];
  v4u o;
  o.x = pack4(a.x, a.y, a.z, a.w);
  o.y = pack4(b.x, b.y, b.z, b.w);
  o.z = pack4(c.x, c.y, c.z, c.w);
  o.w = pack4(d.x, d.y, d.z, d.w);
  w8[i] = o;
}

// ---------------- Kernel 1: quantize fp32 -> int8 --------------------------
// Exact fp32 division + RNE to match jnp.round(x / INPUT_SCALE).
__global__ __launch_bounds__(256) void quant_kernel(
    const float4* __restrict__ x, v4u* __restrict__ xq, int n16) {
  int i = blockIdx.x * 256 + threadIdx.x;
  if (i >= n16) return;
  v4u o;
#pragma unroll
  for (int j = 0; j < 4; ++j) {
    float4 v = x[i * 4 + j];
    float r0 = fminf(fmaxf(rintf(v.x / 0.05f), -128.f), 127.f);
    float r1 = fminf(fmaxf(rintf(v.y / 0.05f), -128.f), 127.f);
    float r2 = fminf(fmaxf(rintf(v.z / 0.05f), -128.f), 127.f);
    float r3 = fminf(fmaxf(rintf(v.w / 0.05f), -128.f), 127.f);
    o[j] = pack4((int)r0, (int)r1, (int)r2, (int)r3);
  }
  xq[i] = o;
}

// ---------------- Kernel 2: int8 GEMM, single-barrier overlapped tile ------
// 256x256 tile, 8 waves (2M x 4N), wave tile 128x64. BK=128 B -> 2 k-slices
// of 64 per MFMA; 64 MFMA/wave/tile in 4 quadrants of 16.
//
// Round-4 post-mortem: per-phase {barrier; lgkm(0); MFMA; barrier} phase-
// locked all waves -> LDS-port time (192 b128 x 12cy = 2304 cy/CU/tile) and
// MFMA time (2612 cy) SERIALIZED (5234 cy/tile measured). This version has
// ONE barrier + ONE vmcnt(0) per tile (DMAs drained were issued a full tile
// earlier -> free). Reads hoisted with counted lgkmcnt so waves stagger
// through the LDS queue while matrix pipes run:
//   [12 reads b0,a0][SB][4 reads b1][SB][8 DMA stage t+1]
//   lgkm(4)  -> Q00 (b1 in flight)
//   lgkm(0)  -> Q01
//   [8 reads a1] lgkm(0) -> Q11, Q10   (a1 after Q01 caps frag liveness
//                                       at 16 v4i -> no spill)
//   vmcnt(0); barrier
// sched_barrier(0) after every inline-asm wait (rule 18: hipcc hoists
// register-only MFMA past asm waitcnt otherwise) and between read groups
// (counted lgkm semantics require issue order).
//
// LDS slot safety with a single barrier: reads of tile t (slot rs) are all
// lgkm-retired before each wave reaches the tile-end barrier; staging of
// t+2 into rs is issued only after that barrier. DMA for t+1 -> ws never
// conflicts with rs reads. Tile t+1's data is vmcnt(0)-retired + barriered
// before t+1's reads.
//
// Swizzle (verified, 0 conflicts): 16B chunk kv of row r at phys chunk
// kv ^ (r&7); staging permutes the per-lane GLOBAL source address
// (global_load_lds LDS dst is rigid: base + lane*16). Stripe-interleaved
// halves kept from round 4 (A by 64-row, B by 32-row stripes).
//
// XCD swizzle: 512 blocks = 32 m x 16 n; 2 n-blocks per XCD.
__global__ __launch_bounds__(512, 1) void gemm_i8_kernel(
    const int8_t* __restrict__ A,     // [M, K] quantized activations
    const int8_t* __restrict__ B,     // [N, K] weight (packed int8)
    const float* __restrict__ bias,   // [N]
    float* __restrict__ C,            // [M, N]
    int M) {
  extern __shared__ __align__(16) int8_t lds[];

  const int tid  = threadIdx.x;
  const int lane = tid & 63;
  const int wave = tid >> 6;
  const int wm   = wave >> 2;   // 0..1  (128-row band)
  const int wn   = wave & 3;    // 0..3  (64-col band)
  const int quad = lane >> 4;
  const int lrow = lane & 15;
  const int k7   = lrow & 7;

  const int bid   = blockIdx.x;
  const int xcd   = bid & 7;
  const int slot  = bid >> 3;            // 0..63
  const int n_blk = xcd * 2 + (slot & 1);
  const int m_blk = slot >> 1;           // 0..31
  const int m0 = m_blk * BM;
  const int n0 = n_blk * BN;

  // Fragment read bases (byte offsets; add slot base at use).
  const int cs0  = (quad ^ k7) * 16;        // k-slice 0 chunk (swizzled)
  const int cs1  = ((4 + quad) ^ k7) * 16;  // k-slice 1 chunk
  const int aoff = (wm * 64 + lrow) * 128;          // A region, a-half 0
  const int boff = REG_A + (wn * 32 + lrow) * 128;  // B region, b-half 0

  // Staging source pointers (stripe-interleaved halves, inverse swizzle on
  // the global chunk). Chunk c = q*512 + tid; idx = c>>3 = row-in-half.
  const int8_t *pAe[2], *pAo[2], *pBe[2], *pBo[2];
  int dstc[2];
#pragma unroll
  for (int q = 0; q < 2; ++q) {
    int c   = q * 512 + tid;
    int idx = c >> 3;
    int lc  = (c & 7) ^ (idx & 7);
    int gA  = ((idx & 64) << 1) | (idx & 63);   // A-even stripe row
    int gB  = ((idx & 96) << 1) | (idx & 31);   // B-even stripe row
    pAe[q] = A + (size_t)(m0 + gA) * K_DIM + lc * 16;
    pAo[q] = A + (size_t)(m0 + gA + 64) * K_DIM + lc * 16;
    pBe[q] = B + (size_t)(n0 + gB) * K_DIM + lc * 16;
    pBo[q] = B + (size_t)(n0 + gB + 32) * K_DIM + lc * 16;
    dstc[q] = c * 16;
  }

#define ST_ALL(ws) { \
    load_lds16(pAe[0], lds + (ws) + dstc[0]); \
    load_lds16(pAe[1], lds + (ws) + dstc[1]); \
    load_lds16(pAo[0], lds + (ws) + HALF + dstc[0]); \
    load_lds16(pAo[1], lds + (ws) + HALF + dstc[1]); \
    load_lds16(pBe[0], lds + (ws) + REG_A + dstc[0]); \
    load_lds16(pBe[1], lds + (ws) + REG_A + dstc[1]); \
    load_lds16(pBo[0], lds + (ws) + REG_A + HALF + dstc[0]); \
    load_lds16(pBo[1], lds + (ws) + REG_A + HALF + dstc[1]); \
    pAe[0] += BK; pAe[1] += BK; pAo[0] += BK; pAo[1] += BK; \
    pBe[0] += BK; pBe[1] += BK; pBo[0] += BK; pBo[1] += BK; }
#define MFMA(d, x, y) d = __builtin_amdgcn_mfma_i32_16x16x64_i8(x, y, d, 0, 0, 0)

  // Prologue: stage tile 0 into slot 0, drain, sync.
  ST_ALL(0);
  asm volatile("s_waitcnt vmcnt(0)" ::: "memory");
  __builtin_amdgcn_s_barrier();
  __builtin_amdgcn_sched_barrier(0);

  v4i acc[8][4] = {};

#pragma unroll 1
  for (int t = 0; t < NT; ++t) {
    const int rs = (t & 1) * SLOT;
    const int ws = rs ^ SLOT;
    const bool pf = (t < NT - 1);
    v4i a0[4][2], a1[4][2], b0[2][2], b1[2][2];

    // ---- read group 1: b0 (4) + a0 (8) ----
#pragma unroll
    for (int j = 0; j < 2; ++j) {
      b0[j][0] = *(const v4i*)(lds + rs + boff + j * 2048 + cs0);
      b0[j][1] = *(const v4i*)(lds + rs + boff + j * 2048 + cs1);
    }
#pragma unroll
    for (int i = 0; i < 4; ++i) {
      a0[i][0] = *(const v4i*)(lds + rs + aoff + i * 2048 + cs0);
      a0[i][1] = *(const v4i*)(lds + rs + aoff + i * 2048 + cs1);
    }
    __builtin_amdgcn_sched_barrier(0);
    // ---- read group 2: b1 (4) ----
#pragma unroll
    for (int j = 0; j < 2; ++j) {
      b1[j][0] = *(const v4i*)(lds + rs + boff + HALF + j * 2048 + cs0);
      b1[j][1] = *(const v4i*)(lds + rs + boff + HALF + j * 2048 + cs1);
    }
    __builtin_amdgcn_sched_barrier(0);
    // ---- stage tile t+1 (8 DMA, vmcnt only) ----
    if (pf) ST_ALL(ws);

    // ---- Q00: needs group 1 only; b1's 4 reads stay in flight ----
    asm volatile("s_waitcnt lgkmcnt(4)" ::: "memory");
    __builtin_amdgcn_sched_barrier(0);
    __builtin_amdgcn_s_setprio(1);
#pragma unroll
    for (int i = 0; i < 4; ++i)
#pragma unroll
      for (int j = 0; j < 2; ++j) {
        MFMA(acc[i][j], a0[i][0], b0[j][0]);
        MFMA(acc[i][j], a0[i][1], b0[j][1]);
      }
    __builtin_amdgcn_s_setprio(0);
    __builtin_amdgcn_sched_barrier(0);

    // ---- Q01: needs b1 ----
    asm volatile("s_waitcnt lgkmcnt(0)" ::: "memory");
    __builtin_amdgcn_sched_barrier(0);
    __builtin_amdgcn_s_setprio(1);
#pragma unroll
    for (int i = 0; i < 4; ++i)
#pragma unroll
      for (int j = 0; j < 2; ++j) {
        MFMA(acc[i][2 + j], a0[i][0], b1[j][0]);
        MFMA(acc[i][2 + j], a0[i][1], b1[j][1]);
      }
    __builtin_amdgcn_s_setprio(0);
    __builtin_amdgcn_sched_barrier(0);

    // ---- read group 3: a1 (8; a0 now dead -> peak 16 v4i frags) ----
#pragma unroll
    for (int i = 0; i < 4; ++i) {
      a1[i][0] = *(const v4i*)(lds + rs + aoff + HALF + i * 2048 + cs0);
      a1[i][1] = *(const v4i*)(lds + rs + aoff + HALF + i * 2048 + cs1);
    }
    asm volatile("s_waitcnt lgkmcnt(0)" ::: "memory");
    __builtin_amdgcn_sched_barrier(0);
    __builtin_amdgcn_s_setprio(1);
#pragma unroll
    for (int i = 0; i < 4; ++i)
#pragma unroll
      for (int j = 0; j < 2; ++j) {
        MFMA(acc[4 + i][2 + j], a1[i][0], b1[j][0]);
        MFMA(acc[4 + i][2 + j], a1[i][1], b1[j][1]);
      }
#pragma unroll
    for (int i = 0; i < 4; ++i)
#pragma unroll
      for (int j = 0; j < 2; ++j) {
        MFMA(acc[4 + i][j], a1[i][0], b0[j][0]);
        MFMA(acc[4 + i][j], a1[i][1], b0[j][1]);
      }
    __builtin_amdgcn_s_setprio(0);
    __builtin_amdgcn_sched_barrier(0);

    // ---- tile boundary: t+1's DMAs (issued ~a full tile ago) drained ----
    if (pf) {
      asm volatile("s_waitcnt vmcnt(0)" ::: "memory");
      __builtin_amdgcn_s_barrier();
      __builtin_amdgcn_sched_barrier(0);
    }
  }
#undef ST_ALL
#undef MFMA

  // Epilogue: y = 0.01 * acc + bias[n]
  // acc[p][jj]: row = wm*128 + (p>>2)*64 + (p&3)*16, col = wn*64 +
  // (jj>>1)*32 + (jj&1)*16. C/D frag: col = lane&15, row = quad*4 + r.
#pragma unroll
  for (int jj = 0; jj < 4; ++jj) {
    const int n = n0 + wn * 64 + (jj >> 1) * 32 + (jj & 1) * 16 + lrow;
    const float bn = bias[n];
#pragma unroll
    for (int p = 0; p < 8; ++p) {
      const int mb = m0 + wm * 128 + (p >> 2) * 64 + (p & 3) * 16 + quad * 4;
#pragma unroll
      for (int r = 0; r < 4; ++r)
        C[(size_t)(mb + r) * N_DIM + n] = 0.01f * (float)acc[p][jj][r] + bn;
    }
  }
}

extern "C" void kernel_launch(void* const* d_in, const int* in_sizes, int n_in,
                              void* d_out, int out_size, void* d_ws, size_t ws_size,
                              hipStream_t stream) {
  static bool inited = false;
  if (!inited) {
    (void)hipFuncSetAttribute(reinterpret_cast<const void*>(gemm_i8_kernel),
                              hipFuncAttributeMaxDynamicSharedMemorySize,
                              LDS_BYTES);
    inited = true;
  }

  const float* x    = (const float*)d_in[0];
  const int*   w32  = (const int*)d_in[1];   // harness stores int8 input as int32
  const float* bias = (const float*)d_in[2];
  float* out = (float*)d_out;
  const int M = in_sizes[0] / K_DIM;  // 8192

  int8_t* xq = (int8_t*)d_ws;                              // M*K
  int8_t* wq = (int8_t*)d_ws + (size_t)M * K_DIM;          // N*K

  const int nw16 = (N_DIM * K_DIM) / 16;
  pack_w_kernel<<<(nw16 + 255) / 256, 256, 0, stream>>>(
      (const int4*)w32, (v4u*)wq, nw16);

  const int n16 = (M * K_DIM) / 16;
  quant_kernel<<<(n16 + 255) / 256, 256, 0, stream>>>(
      (const float4*)x, (v4u*)xq, n16);

  const int nblocks = (M / BM) * (N_DIM / BN);  // 512
  gemm_i8_kernel<<<nblocks, 512, LDS_BYTES, stream>>>(xq, wq, bias, out, M);
}